// Round 3
// baseline (80.027 us; speedup 1.0000x reference)
//
#include <hip/hip_runtime.h>
#include <hip/hip_bf16.h>

// MultiHeadAttention: N=4, S=1024, D=512, H=8, dh=64. f32 in/out, bf16 compute.
// Pipeline: [qkv_gemm z=3] -> [attn] -> [out_gemm]
// ws layout (bf16): Qb[4096*512] | Kb[4096*512] | Vt[32*64*1024] | AO[4096*512]

typedef short bf16x8 __attribute__((ext_vector_type(8)));
typedef float f32x4 __attribute__((ext_vector_type(4)));
typedef int   i32x4 __attribute__((ext_vector_type(4)));
typedef unsigned short u16;
typedef unsigned int   u32;

#define MFMA_BF16(A, B, C) __builtin_amdgcn_mfma_f32_16x16x32_bf16((A), (B), (C), 0, 0, 0)

__device__ __forceinline__ float bf2f(u16 h) {
    u32 u = ((u32)h) << 16;
    return __builtin_bit_cast(float, u);
}
__device__ __forceinline__ u16 f2bf(float f) {
    u32 u = __builtin_bit_cast(u32, f);
    u32 r = (u + 0x7fffu + ((u >> 16) & 1u)) >> 16;  // RNE
    return (u16)r;
}

// C = X @ W^T + bias.  X:[4096][512], W:[512][512] (both row-major, K inner).
// AMODE: 0 = X is f32 (convert to bf16 while staging), 1 = X is bf16 (u16).
// OMODE: 0 = f32 out[4096][512], 1 = bf16 out[4096][512],
//        2 = bf16 Vt[mh=n*8+h][d][s] (per-head transposed).
template <int AMODE, int OMODE>
__device__ __forceinline__ void gemm_body(const void* __restrict__ X_,
                                          const float* __restrict__ W,
                                          const float* __restrict__ bias,
                                          void* __restrict__ out_) {
    __shared__ alignas(16) char As[128 * 128];  // 128 rows x 64 bf16, swizzled
    __shared__ alignas(16) char Bs[128 * 128];

    const int tid = threadIdx.x;
    const int m0 = blockIdx.x * 128;
    const int n0 = blockIdx.y * 128;
    const int w = tid >> 6, l = tid & 63;
    const int wm = (w >> 1) * 64, wn = (w & 1) * 64;
    const int lg = l >> 4, lr = l & 15;

    f32x4 acc[4][4];
#pragma unroll
    for (int i = 0; i < 4; i++)
#pragma unroll
        for (int j = 0; j < 4; j++) acc[i][j] = (f32x4){0.f, 0.f, 0.f, 0.f};

    for (int k0 = 0; k0 < 512; k0 += 64) {
        // Stage 128x64 of X and W into LDS, XOR-swizzled (byte ^= (row&7)<<4).
#pragma unroll
        for (int p = 0; p < 4; p++) {
            int idx = p * 256 + tid;
            int row = idx >> 3, c8 = idx & 7;
            int swz = (c8 * 16) ^ ((row & 7) << 4);
            // A side
            if (AMODE == 0) {
                const float* ap = (const float*)X_ + (size_t)(m0 + row) * 512 + k0 + c8 * 8;
                f32x4 a0 = *reinterpret_cast<const f32x4*>(ap);
                f32x4 a1 = *reinterpret_cast<const f32x4*>(ap + 4);
                i32x4 pk;
                pk[0] = (u32)f2bf(a0[0]) | ((u32)f2bf(a0[1]) << 16);
                pk[1] = (u32)f2bf(a0[2]) | ((u32)f2bf(a0[3]) << 16);
                pk[2] = (u32)f2bf(a1[0]) | ((u32)f2bf(a1[1]) << 16);
                pk[3] = (u32)f2bf(a1[2]) | ((u32)f2bf(a1[3]) << 16);
                *reinterpret_cast<i32x4*>(As + row * 128 + swz) = pk;
            } else {
                const u16* ap = (const u16*)X_ + (size_t)(m0 + row) * 512 + k0 + c8 * 8;
                *reinterpret_cast<i32x4*>(As + row * 128 + swz) =
                    *reinterpret_cast<const i32x4*>(ap);
            }
            // B side (weights, always f32)
            const float* wp = W + (size_t)(n0 + row) * 512 + k0 + c8 * 8;
            f32x4 w0 = *reinterpret_cast<const f32x4*>(wp);
            f32x4 w1 = *reinterpret_cast<const f32x4*>(wp + 4);
            i32x4 wk;
            wk[0] = (u32)f2bf(w0[0]) | ((u32)f2bf(w0[1]) << 16);
            wk[1] = (u32)f2bf(w0[2]) | ((u32)f2bf(w0[3]) << 16);
            wk[2] = (u32)f2bf(w1[0]) | ((u32)f2bf(w1[1]) << 16);
            wk[3] = (u32)f2bf(w1[2]) | ((u32)f2bf(w1[3]) << 16);
            *reinterpret_cast<i32x4*>(Bs + row * 128 + swz) = wk;
        }
        __syncthreads();
#pragma unroll
        for (int kk = 0; kk < 64; kk += 32) {
            bf16x8 af[4], bfr[4];
#pragma unroll
            for (int i = 0; i < 4; i++) {
                int ra = wm + i * 16 + lr;
                af[i] = *reinterpret_cast<const bf16x8*>(
                    As + ra * 128 + ((kk * 2 + lg * 16) ^ ((ra & 7) << 4)));
                int rb = wn + i * 16 + lr;
                bfr[i] = *reinterpret_cast<const bf16x8*>(
                    Bs + rb * 128 + ((kk * 2 + lg * 16) ^ ((rb & 7) << 4)));
            }
#pragma unroll
            for (int i = 0; i < 4; i++)
#pragma unroll
                for (int j = 0; j < 4; j++) acc[i][j] = MFMA_BF16(af[i], bfr[j], acc[i][j]);
        }
        __syncthreads();
    }

    // Epilogue: bias add (f32), store. D layout: row=(l>>4)*4+r, col=l&15.
#pragma unroll
    for (int j = 0; j < 4; j++) {
        int col = n0 + wn + j * 16 + lr;
        float bc = bias[col];
#pragma unroll
        for (int i = 0; i < 4; i++) {
            int grbase = m0 + wm + i * 16 + lg * 4;
            if (OMODE == 0) {
                float* out = (float*)out_;
#pragma unroll
                for (int r = 0; r < 4; r++)
                    out[(size_t)(grbase + r) * 512 + col] = acc[i][j][r] + bc;
            } else if (OMODE == 1) {
                u16* out = (u16*)out_;
#pragma unroll
                for (int r = 0; r < 4; r++)
                    out[(size_t)(grbase + r) * 512 + col] = f2bf(acc[i][j][r] + bc);
            } else {
                // Vt[mh][d][s]: 4 consecutive tokens are contiguous -> 8B store
                u16* out = (u16*)out_;
                int mh = ((grbase >> 10) * 8) + (col >> 6);
                int t = grbase & 1023;
                u32 p0 = (u32)f2bf(acc[i][j][0] + bc) | ((u32)f2bf(acc[i][j][1] + bc) << 16);
                u32 p1 = (u32)f2bf(acc[i][j][2] + bc) | ((u32)f2bf(acc[i][j][3] + bc) << 16);
                u32* dst = reinterpret_cast<u32*>(out + ((size_t)mh * 64 + (col & 63)) * 1024 + t);
                dst[0] = p0;
                dst[1] = p1;
            }
        }
    }
}

__global__ __launch_bounds__(256) void qkv_gemm(
    const float* __restrict__ Xq, const float* __restrict__ Xk, const float* __restrict__ Xv,
    const float* __restrict__ Wq, const float* __restrict__ Wk, const float* __restrict__ Wv,
    const float* __restrict__ bq, const float* __restrict__ bk, const float* __restrict__ bv,
    u16* __restrict__ Qb, u16* __restrict__ Kb, u16* __restrict__ Vt) {
    int z = blockIdx.z;
    if (z == 0)      gemm_body<0, 1>(Xq, Wq, bq, Qb);
    else if (z == 1) gemm_body<0, 1>(Xk, Wk, bk, Kb);
    else             gemm_body<0, 2>(Xv, Wv, bv, Vt);
}

__global__ __launch_bounds__(256) void out_gemm(const u16* __restrict__ AO,
                                                const float* __restrict__ Wo,
                                                const float* __restrict__ bo,
                                                float* __restrict__ out) {
    gemm_body<1, 0>(AO, Wo, bo, out);
}

// Flash-style masked attention. One wave = 16 q-rows of one head; s-tiles of 32.
// Swapped QK^T: S^T = mfma(A=K, B=Q) so each lane's 8 score elems share q = l&15
// (row stats lane-local + 2 shfl_xor). Mask: attend iff s < prefix[n] || s == q.
// Only tiles [0, ceil(prefix/32)) plus the diagonal tile are processed.
__global__ __launch_bounds__(256) void attn_kernel(const u16* __restrict__ Qb,
                                                   const u16* __restrict__ Kb,
                                                   const u16* __restrict__ Vt,
                                                   const int* __restrict__ prefix,
                                                   u16* __restrict__ AO) {
    const int tid = threadIdx.x;
    const int w = tid >> 6, l = tid & 63;
    const int lg = l >> 4, lr = l & 15;
    const int qblk = blockIdx.x;  // 0..15
    const int m = blockIdx.y;     // 0..31 (n*8+h)
    const int n = m >> 3, h = m & 7;
    const int q0 = qblk * 64 + w * 16;
    const int P = prefix[n];

    // Q fragments (B operand). Scores scaled by 1/sqrt(dh)=0.125 AFTER the MFMA.
    const u16* qptr = Qb + (size_t)(n * 1024 + q0 + lr) * 512 + h * 64 + lg * 8;
    bf16x8 qf0 = *reinterpret_cast<const bf16x8*>(qptr);
    bf16x8 qf1 = *reinterpret_cast<const bf16x8*>(qptr + 32);

    f32x4 o[4];
#pragma unroll
    for (int j = 0; j < 4; j++) o[j] = (f32x4){0.f, 0.f, 0.f, 0.f};
    float mrow = -1.0e9f, lsum = 0.f;

    const int T = (P + 31) >> 5;
    const int dt = q0 >> 5;
    const int nt = T + ((dt >= T) ? 1 : 0);
    const int q_glob = q0 + lr;
    const f32x4 fz = (f32x4){0.f, 0.f, 0.f, 0.f};

    for (int it = 0; it < nt; ++it) {
        const int s0 = ((it < T) ? it : dt) << 5;
        const u16* kptr = Kb + (size_t)(n * 1024 + s0 + lr) * 512 + h * 64 + lg * 8;
        bf16x8 ak00 = *reinterpret_cast<const bf16x8*>(kptr);
        bf16x8 ak01 = *reinterpret_cast<const bf16x8*>(kptr + 32);
        bf16x8 ak10 = *reinterpret_cast<const bf16x8*>(kptr + 16 * 512);
        bf16x8 ak11 = *reinterpret_cast<const bf16x8*>(kptr + 16 * 512 + 32);

        f32x4 st[2];
        st[0] = MFMA_BF16(ak00, qf0, fz);
        st[0] = MFMA_BF16(ak01, qf1, st[0]);
        st[1] = MFMA_BF16(ak10, qf0, fz);
        st[1] = MFMA_BF16(ak11, qf1, st[1]);

        // Scale, clamp, mask. S^T layout: lane elem (c,r) is s = s0+16c+4*lg+r.
#pragma unroll
        for (int c = 0; c < 2; c++)
#pragma unroll
            for (int r = 0; r < 4; r++) {
                int s = s0 + c * 16 + lg * 4 + r;
                float v = fminf(st[c][r] * 0.125f, 1.0e4f);
                st[c][r] = ((s < P) || (s == q_glob)) ? v : -1.0e9f;
            }

        // Online softmax: per-q stats (lane-local over 8, then xor 16/32).
        float tm = st[0][0];
#pragma unroll
        for (int r = 1; r < 4; r++) tm = fmaxf(tm, st[0][r]);
#pragma unroll
        for (int r = 0; r < 4; r++) tm = fmaxf(tm, st[1][r]);
        tm = fmaxf(tm, __shfl_xor(tm, 16));
        tm = fmaxf(tm, __shfl_xor(tm, 32));
        float Mn = fmaxf(mrow, tm);       // in [-1e9, 1e4]
        float alpha = __expf(mrow - Mn);  // arg <= 0 always
        float ts = 0.f;
#pragma unroll
        for (int c = 0; c < 2; c++)
#pragma unroll
            for (int r = 0; r < 4; r++) {
                float p = __expf(st[c][r] - Mn);  // arg <= 0 always
                st[c][r] = p;
                ts += p;
            }
        ts += __shfl_xor(ts, 16);
        ts += __shfl_xor(ts, 32);
        lsum = lsum * alpha + ts;
        mrow = Mn;

        // Rescale O (O rows are q=4*lg+r; alpha lives at lane lr==q).
        float a4[4];
#pragma unroll
        for (int r = 0; r < 4; r++) a4[r] = __shfl(alpha, lg * 4 + r);
#pragma unroll
        for (int j = 0; j < 4; j++) {
            o[j][0] *= a4[0]; o[j][1] *= a4[1]; o[j][2] *= a4[2]; o[j][3] *= a4[3];
        }

        // P^T -> PV A-frag (P[q][8*lg+e]) via packed bf16 pairs + shfl gather.
        u32 pk[2][2];
#pragma unroll
        for (int c = 0; c < 2; c++) {
            pk[c][0] = (u32)f2bf(st[c][0]) | ((u32)f2bf(st[c][1]) << 16);
            pk[c][1] = (u32)f2bf(st[c][2]) | ((u32)f2bf(st[c][3]) << 16);
        }
        i32x4 pav;
#pragma unroll
        for (int wd = 0; wd < 4; wd++) {
            int src = ((2 * (lg & 1) + (wd >> 1)) << 4) + lr;
            int t0 = __shfl((int)pk[0][wd & 1], src);
            int t1 = __shfl((int)pk[1][wd & 1], src);
            pav[wd] = (lg >> 1) ? t1 : t0;
        }
        bf16x8 paf = __builtin_bit_cast(bf16x8, pav);

        // PV: B-frag from Vt[m][d][s] (contiguous along s).
        const u16* vptr = Vt + ((size_t)m * 64 + lr) * 1024 + s0 + lg * 8;
#pragma unroll
        for (int j = 0; j < 4; j++) {
            bf16x8 bv = *reinterpret_cast<const bf16x8*>(vptr + (size_t)j * 16 * 1024);
            o[j] = MFMA_BF16(paf, bv, o[j]);
        }
    }

    float linv = 1.0f / fmaxf(lsum, 1.0e-30f);
    float li[4];
#pragma unroll
    for (int r = 0; r < 4; r++) li[r] = __shfl(linv, lg * 4 + r);

    u16* obase = AO + (size_t)(n * 1024 + q0 + lg * 4) * 512 + h * 64 + lr;
#pragma unroll
    for (int j = 0; j < 4; j++)
#pragma unroll
        for (int r = 0; r < 4; r++) {
            float v = fminf(fmaxf(o[j][r] * li[r], -1.0e4f), 1.0e4f);
            obase[(size_t)r * 512 + j * 16] = f2bf(v);
        }
}

extern "C" void kernel_launch(void* const* d_in, const int* in_sizes, int n_in,
                              void* d_out, int out_size, void* d_ws, size_t ws_size,
                              hipStream_t stream) {
    (void)in_sizes; (void)n_in; (void)out_size;
    const float* queries = (const float*)d_in[0];
    const float* keys    = (const float*)d_in[1];
    const float* values  = (const float*)d_in[2];
    const int*   prefix  = (const int*)d_in[3];
    const float* Wq = (const float*)d_in[4];
    const float* bq = (const float*)d_in[5];
    const float* Wk = (const float*)d_in[6];
    const float* bk = (const float*)d_in[7];
    const float* Wv = (const float*)d_in[8];
    const float* bv = (const float*)d_in[9];
    const float* Wo = (const float*)d_in[10];
    const float* bo = (const float*)d_in[11];
    float* outp = (float*)d_out;

    const size_t SLAB = (size_t)4096 * 512;  // bf16 elements per buffer
    if (ws_size < 4 * SLAB * sizeof(u16)) return;
    u16* Qb = (u16*)d_ws;
    u16* Kb = Qb + SLAB;
    u16* Vt = Kb + SLAB;
    u16* AO = Vt + SLAB;

    dim3 blk(256);
    qkv_gemm<<<dim3(32, 4, 3), blk, 0, stream>>>(queries, keys, values, Wq, Wk, Wv,
                                                 bq, bk, bv, Qb, Kb, Vt);
    attn_kernel<<<dim3(16, 32), blk, 0, stream>>>(Qb, Kb, Vt, prefix, AO);
    out_gemm<<<dim3(32, 4, 1), blk, 0, stream>>>(AO, Wo, bo, outp);
}

// Round 4
// 73.815 us; speedup vs baseline: 1.0842x; 1.0842x over previous
//
#include <hip/hip_runtime.h>
#include <hip/hip_bf16.h>

// MultiHeadAttention: N=4, S=1024, D=512, H=8, dh=64. f32 in/out, bf16 compute.
// Pipeline: [qkv_gemm z=3] -> [attn] -> [out_gemm]
// ws layout (bf16): Qb[4096*512] | Kb[4096*512] | Vt[32*64*1024] | AO[4096*512]
// Qb holds Q pre-scaled by 1/sqrt(dh)=0.125 (folded into projection epilogue).

typedef short bf16x8 __attribute__((ext_vector_type(8)));
typedef float f32x4 __attribute__((ext_vector_type(4)));
typedef int   i32x4 __attribute__((ext_vector_type(4)));
typedef unsigned short u16;
typedef unsigned int   u32;

#define MFMA_BF16(A, B, C) __builtin_amdgcn_mfma_f32_16x16x32_bf16((A), (B), (C), 0, 0, 0)

__device__ __forceinline__ u16 cvt_bf16(float f) {
    return __builtin_bit_cast(u16, __float2bfloat16(f));  // RNE, fuses to v_cvt_pk_bf16_f32
}
__device__ __forceinline__ u32 cvt2(float lo, float hi) {
    return (u32)cvt_bf16(lo) | ((u32)cvt_bf16(hi) << 16);
}
__device__ __forceinline__ i32x4 cvt8(f32x4 a, f32x4 b) {
    i32x4 r;
    r[0] = cvt2(a[0], a[1]); r[1] = cvt2(a[2], a[3]);
    r[2] = cvt2(b[0], b[1]); r[3] = cvt2(b[2], b[3]);
    return r;
}

// C = (X @ W^T + bias) * scale.  X:[4096][512], W:[512][512] (row-major, K inner).
// AMODE: 0 = X f32 (cvt while staging), 1 = X bf16.
// OMODE: 0 = f32 out[4096][512], 1 = bf16 out[4096][512],
//        2 = bf16 Vt[mh=n*8+h][d][s] (per-head transposed).
// Double-buffered LDS (T14 split: issue loads early, cvt+write after compute).
template <int AMODE, int OMODE>
__device__ __forceinline__ void gemm_body(const void* __restrict__ X_,
                                          const float* __restrict__ W,
                                          const float* __restrict__ bias,
                                          void* __restrict__ out_, float scale) {
    __shared__ alignas(16) char As[2][16384];  // 128 rows x 64 bf16, swizzled
    __shared__ alignas(16) char Bs[2][16384];

    const int tid = threadIdx.x;
    const int m0 = blockIdx.x * 128;
    const int n0 = blockIdx.y * 128;
    const int w = tid >> 6, l = tid & 63;
    const int wm = (w >> 1) * 64, wn = (w & 1) * 64;
    const int lg = l >> 4, lr = l & 15;

    // Staging map: per p (0..3), row = p*32 + (tid>>3), col8 = tid&7.
    const int grow = tid >> 3, gc8 = tid & 7;
    const int ldsb = grow * 128 + ((gc8 * 16) ^ ((grow & 7) << 4));  // + p*4096

    f32x4 ra[4][2], rb[4][2];
    i32x4 rab[4];

    auto LOAD = [&](int k0) {
#pragma unroll
        for (int p = 0; p < 4; p++) {
            if (AMODE == 0) {
                const float* ap = (const float*)X_ + (size_t)(m0 + p * 32 + grow) * 512 + k0 + gc8 * 8;
                ra[p][0] = *reinterpret_cast<const f32x4*>(ap);
                ra[p][1] = *reinterpret_cast<const f32x4*>(ap + 4);
            } else {
                const u16* ap = (const u16*)X_ + (size_t)(m0 + p * 32 + grow) * 512 + k0 + gc8 * 8;
                rab[p] = *reinterpret_cast<const i32x4*>(ap);
            }
            const float* wp = W + (size_t)(n0 + p * 32 + grow) * 512 + k0 + gc8 * 8;
            rb[p][0] = *reinterpret_cast<const f32x4*>(wp);
            rb[p][1] = *reinterpret_cast<const f32x4*>(wp + 4);
        }
    };
    auto WRITE = [&](int buf) {
#pragma unroll
        for (int p = 0; p < 4; p++) {
            if (AMODE == 0)
                *reinterpret_cast<i32x4*>(As[buf] + p * 4096 + ldsb) = cvt8(ra[p][0], ra[p][1]);
            else
                *reinterpret_cast<i32x4*>(As[buf] + p * 4096 + ldsb) = rab[p];
            *reinterpret_cast<i32x4*>(Bs[buf] + p * 4096 + ldsb) = cvt8(rb[p][0], rb[p][1]);
        }
    };

    f32x4 acc[4][4];
#pragma unroll
    for (int i = 0; i < 4; i++)
#pragma unroll
        for (int j = 0; j < 4; j++) acc[i][j] = (f32x4){0.f, 0.f, 0.f, 0.f};

    auto COMPUTE = [&](int buf) {
#pragma unroll
        for (int kk = 0; kk < 2; kk++) {
            bf16x8 af[4], bfr[4];
#pragma unroll
            for (int i = 0; i < 4; i++) {
                int ra_ = wm + i * 16 + lr;
                af[i] = *reinterpret_cast<const bf16x8*>(
                    As[buf] + ra_ * 128 + ((kk * 64 + lg * 16) ^ ((ra_ & 7) << 4)));
                int rb_ = wn + i * 16 + lr;
                bfr[i] = *reinterpret_cast<const bf16x8*>(
                    Bs[buf] + rb_ * 128 + ((kk * 64 + lg * 16) ^ ((rb_ & 7) << 4)));
            }
#pragma unroll
            for (int i = 0; i < 4; i++)
#pragma unroll
                for (int j = 0; j < 4; j++) acc[i][j] = MFMA_BF16(af[i], bfr[j], acc[i][j]);
        }
    };

    LOAD(0);
    WRITE(0);
    __syncthreads();
#pragma unroll
    for (int t = 0; t < 8; t++) {
        if (t < 7) LOAD((t + 1) * 64);  // issue early: latency hides under COMPUTE
        COMPUTE(t & 1);
        if (t < 7) {
            __syncthreads();
            WRITE((t + 1) & 1);
            __syncthreads();
        }
    }

    // Epilogue: (acc + bias) * scale. D layout: row=(l>>4)*4+r, col=l&15.
#pragma unroll
    for (int j = 0; j < 4; j++) {
        int col = n0 + wn + j * 16 + lr;
        float bc = bias[col];
#pragma unroll
        for (int i = 0; i < 4; i++) {
            int grbase = m0 + wm + i * 16 + lg * 4;
            if (OMODE == 0) {
                float* out = (float*)out_;
#pragma unroll
                for (int r = 0; r < 4; r++)
                    out[(size_t)(grbase + r) * 512 + col] = (acc[i][j][r] + bc) * scale;
            } else if (OMODE == 1) {
                u16* out = (u16*)out_;
#pragma unroll
                for (int r = 0; r < 4; r++)
                    out[(size_t)(grbase + r) * 512 + col] = cvt_bf16((acc[i][j][r] + bc) * scale);
            } else {
                // Vt[mh][d][s]: 4 consecutive tokens contiguous -> 2x4B store
                u16* out = (u16*)out_;
                int mh = ((grbase >> 10) * 8) + (col >> 6);
                int t2 = grbase & 1023;
                u32 p0 = cvt2((acc[i][j][0] + bc) * scale, (acc[i][j][1] + bc) * scale);
                u32 p1 = cvt2((acc[i][j][2] + bc) * scale, (acc[i][j][3] + bc) * scale);
                u32* dst = reinterpret_cast<u32*>(out + ((size_t)mh * 64 + (col & 63)) * 1024 + t2);
                dst[0] = p0;
                dst[1] = p1;
            }
        }
    }
}

__global__ __launch_bounds__(256, 2) void qkv_gemm(
    const float* __restrict__ Xq, const float* __restrict__ Xk, const float* __restrict__ Xv,
    const float* __restrict__ Wq, const float* __restrict__ Wk, const float* __restrict__ Wv,
    const float* __restrict__ bq, const float* __restrict__ bk, const float* __restrict__ bv,
    u16* __restrict__ Qb, u16* __restrict__ Kb, u16* __restrict__ Vt) {
    int z = blockIdx.z;
    if (z == 0)      gemm_body<0, 1>(Xq, Wq, bq, Qb, 0.125f);  // Q pre-scaled
    else if (z == 1) gemm_body<0, 1>(Xk, Wk, bk, Kb, 1.0f);
    else             gemm_body<0, 2>(Xv, Wv, bv, Vt, 1.0f);
}

__global__ __launch_bounds__(256, 2) void out_gemm(const u16* __restrict__ AO,
                                                   const float* __restrict__ Wo,
                                                   const float* __restrict__ bo,
                                                   float* __restrict__ out) {
    gemm_body<1, 0>(AO, Wo, bo, out, 1.0f);
}

// Flash-style masked attention. One wave = 16 q-rows of one head; s-tiles of 32.
// Swapped QK^T: S^T = mfma(A=K, B=Q); q = l&15 lane-local row stats.
// Mask: attend iff s < prefix[n] || s == q. Q already carries the 0.125 scale.
__global__ __launch_bounds__(256) void attn_kernel(const u16* __restrict__ Qb,
                                                   const u16* __restrict__ Kb,
                                                   const u16* __restrict__ Vt,
                                                   const int* __restrict__ prefix,
                                                   u16* __restrict__ AO) {
    const int tid = threadIdx.x;
    const int w = tid >> 6, l = tid & 63;
    const int lg = l >> 4, lr = l & 15;
    const int qblk = blockIdx.x;  // 0..15
    const int m = blockIdx.y;     // 0..31 (n*8+h)
    const int n = m >> 3, h = m & 7;
    const int q0 = qblk * 64 + w * 16;
    const int P = prefix[n];

    const u16* qptr = Qb + (size_t)(n * 1024 + q0 + lr) * 512 + h * 64 + lg * 8;
    bf16x8 qf0 = *reinterpret_cast<const bf16x8*>(qptr);
    bf16x8 qf1 = *reinterpret_cast<const bf16x8*>(qptr + 32);

    f32x4 o[4];
#pragma unroll
    for (int j = 0; j < 4; j++) o[j] = (f32x4){0.f, 0.f, 0.f, 0.f};
    float mrow = -1.0e9f, lsum = 0.f;

    const int T = (P + 31) >> 5;
    const int dt = q0 >> 5;
    const int nt = T + ((dt >= T) ? 1 : 0);
    const int q_glob = q0 + lr;
    const f32x4 fz = (f32x4){0.f, 0.f, 0.f, 0.f};

    for (int it = 0; it < nt; ++it) {
        const int s0 = ((it < T) ? it : dt) << 5;
        const u16* kptr = Kb + (size_t)(n * 1024 + s0 + lr) * 512 + h * 64 + lg * 8;
        bf16x8 ak00 = *reinterpret_cast<const bf16x8*>(kptr);
        bf16x8 ak01 = *reinterpret_cast<const bf16x8*>(kptr + 32);
        bf16x8 ak10 = *reinterpret_cast<const bf16x8*>(kptr + 16 * 512);
        bf16x8 ak11 = *reinterpret_cast<const bf16x8*>(kptr + 16 * 512 + 32);

        f32x4 st[2];
        st[0] = MFMA_BF16(ak00, qf0, fz);
        st[0] = MFMA_BF16(ak01, qf1, st[0]);
        st[1] = MFMA_BF16(ak10, qf0, fz);
        st[1] = MFMA_BF16(ak11, qf1, st[1]);

        // Clamp + mask. S^T layout: lane elem (c,r) is s = s0+16c+4*lg+r.
#pragma unroll
        for (int c = 0; c < 2; c++)
#pragma unroll
            for (int r = 0; r < 4; r++) {
                int s = s0 + c * 16 + lg * 4 + r;
                float v = fminf(st[c][r], 1.0e4f);
                st[c][r] = ((s < P) || (s == q_glob)) ? v : -1.0e9f;
            }

        // Online softmax (stats per q: lane-local 8, then xor 16/32).
        float tm = st[0][0];
#pragma unroll
        for (int r = 1; r < 4; r++) tm = fmaxf(tm, st[0][r]);
#pragma unroll
        for (int r = 0; r < 4; r++) tm = fmaxf(tm, st[1][r]);
        tm = fmaxf(tm, __shfl_xor(tm, 16));
        tm = fmaxf(tm, __shfl_xor(tm, 32));
        float Mn = fmaxf(mrow, tm);
        float alpha = __expf(mrow - Mn);
        float ts = 0.f;
#pragma unroll
        for (int c = 0; c < 2; c++)
#pragma unroll
            for (int r = 0; r < 4; r++) {
                float p = __expf(st[c][r] - Mn);
                st[c][r] = p;
                ts += p;
            }
        ts += __shfl_xor(ts, 16);
        ts += __shfl_xor(ts, 32);
        lsum = lsum * alpha + ts;
        mrow = Mn;

        float a4[4];
#pragma unroll
        for (int r = 0; r < 4; r++) a4[r] = __shfl(alpha, lg * 4 + r);
#pragma unroll
        for (int j = 0; j < 4; j++) {
            o[j][0] *= a4[0]; o[j][1] *= a4[1]; o[j][2] *= a4[2]; o[j][3] *= a4[3];
        }

        // P^T -> PV A-frag via packed bf16 pairs + shfl gather.
        u32 pk[2][2];
#pragma unroll
        for (int c = 0; c < 2; c++) {
            pk[c][0] = cvt2(st[c][0], st[c][1]);
            pk[c][1] = cvt2(st[c][2], st[c][3]);
        }
        i32x4 pav;
#pragma unroll
        for (int wd = 0; wd < 4; wd++) {
            int src = ((2 * (lg & 1) + (wd >> 1)) << 4) + lr;
            int t0 = __shfl((int)pk[0][wd & 1], src);
            int t1 = __shfl((int)pk[1][wd & 1], src);
            pav[wd] = (lg >> 1) ? t1 : t0;
        }
        bf16x8 paf = __builtin_bit_cast(bf16x8, pav);

        const u16* vptr = Vt + ((size_t)m * 64 + lr) * 1024 + s0 + lg * 8;
#pragma unroll
        for (int j = 0; j < 4; j++) {
            bf16x8 bv = *reinterpret_cast<const bf16x8*>(vptr + (size_t)j * 16 * 1024);
            o[j] = MFMA_BF16(paf, bv, o[j]);
        }
    }

    float linv = 1.0f / fmaxf(lsum, 1.0e-30f);
    float li[4];
#pragma unroll
    for (int r = 0; r < 4; r++) li[r] = __shfl(linv, lg * 4 + r);

    u16* obase = AO + (size_t)(n * 1024 + q0 + lg * 4) * 512 + h * 64 + lr;
#pragma unroll
    for (int j = 0; j < 4; j++)
#pragma unroll
        for (int r = 0; r < 4; r++) {
            float v = fminf(fmaxf(o[j][r] * li[r], -1.0e4f), 1.0e4f);
            obase[(size_t)r * 512 + j * 16] = cvt_bf16(v);
        }
}

extern "C" void kernel_launch(void* const* d_in, const int* in_sizes, int n_in,
                              void* d_out, int out_size, void* d_ws, size_t ws_size,
                              hipStream_t stream) {
    (void)in_sizes; (void)n_in; (void)out_size;
    const float* queries = (const float*)d_in[0];
    const float* keys    = (const float*)d_in[1];
    const float* values  = (const float*)d_in[2];
    const int*   prefix  = (const int*)d_in[3];
    const float* Wq = (const float*)d_in[4];
    const float* bq = (const float*)d_in[5];
    const float* Wk = (const float*)d_in[6];
    const float* bk = (const float*)d_in[7];
    const float* Wv = (const float*)d_in[8];
    const float* bv = (const float*)d_in[9];
    const float* Wo = (const float*)d_in[10];
    const float* bo = (const float*)d_in[11];
    float* outp = (float*)d_out;

    const size_t SLAB = (size_t)4096 * 512;  // bf16 elements per buffer
    if (ws_size < 4 * SLAB * sizeof(u16)) return;
    u16* Qb = (u16*)d_ws;
    u16* Kb = Qb + SLAB;
    u16* Vt = Kb + SLAB;
    u16* AO = Vt + SLAB;

    dim3 blk(256);
    qkv_gemm<<<dim3(32, 4, 3), blk, 0, stream>>>(queries, keys, values, Wq, Wk, Wv,
                                                 bq, bk, bv, Qb, Kb, Vt);
    attn_kernel<<<dim3(16, 32), blk, 0, stream>>>(Qb, Kb, Vt, prefix, AO);
    out_gemm<<<dim3(32, 4, 1), blk, 0, stream>>>(AO, Wo, bo, outp);
}